// Round 16
// baseline (294.675 us; speedup 1.0000x reference)
//
#include <hip/hip_runtime.h>
#include <hip/hip_fp16.h>
#include <stdint.h>

#define D_DIM 4096
#define H_DIM 4096
#define NSCAN 4096         // scan blocks (one per h-row)
#define NVDOT 2048         // vdot blocks (64 i-tiles x 32 h-tiles)

__device__ __forceinline__ float fast_sigmoid(float a) {
    return __builtin_amdgcn_rcpf(1.0f + __expf(-a));
}

// ---- Fused scan+vdot, ordered-grid producer/consumer -----------------------
// Blocks 0..4095: quarter-split row scan h=bid -> S8 row; release ready[h>>7].
// Blocks 4096..6143: vdot tile (it,ht); v loads pre-issued, acquire-spin on
// ready[ht]==128, then stage S-slab to swizzled LDS and dot.
__global__ __launch_bounds__(256, 8) void nade_fused2_kernel(
    const float* __restrict__ x,
    const float* __restrict__ w,
    const float* __restrict__ v,
    const float* __restrict__ c,
    uint8_t* __restrict__ S8,
    float* __restrict__ part,
    int* __restrict__ ready)
{
    const int tid  = threadIdx.x;
    const int bid  = blockIdx.x;
    const int lane = tid & 63;

    if (bid < NSCAN) {
        // ================= SCAN (R15-exact body) =================
        __shared__ float qtot[4];
        const int q    = tid >> 6;
        const int h    = bid;
        const int col0 = q * 1024 + 8 * lane;

        const float* wp = w + (size_t)h * D_DIM + col0;
        const float* xp = x + col0;

        float4 w00 = *reinterpret_cast<const float4*>(wp);
        float4 w01 = *reinterpret_cast<const float4*>(wp + 4);
        float4 w10 = *reinterpret_cast<const float4*>(wp + 512);
        float4 w11 = *reinterpret_cast<const float4*>(wp + 512 + 4);
        float4 x00 = *reinterpret_cast<const float4*>(xp);
        float4 x01 = *reinterpret_cast<const float4*>(xp + 4);
        float4 x10 = *reinterpret_cast<const float4*>(xp + 512);
        float4 x11 = *reinterpret_cast<const float4*>(xp + 512 + 4);

        float l[16];
        float carry = 0.0f;

        #pragma unroll
        for (int t = 0; t < 2; ++t) {
            const float4 wv0 = t ? w10 : w00;
            const float4 wv1 = t ? w11 : w01;
            const float4 xv0 = t ? x10 : x00;
            const float4 xv1 = t ? x11 : x01;
            float p0 = wv0.x * xv0.x, p1 = wv0.y * xv0.y, p2 = wv0.z * xv0.z, p3 = wv0.w * xv0.w;
            float p4 = wv1.x * xv1.x, p5 = wv1.y * xv1.y, p6 = wv1.z * xv1.z, p7 = wv1.w * xv1.w;
            float s8 = ((p0 + p1) + (p2 + p3)) + ((p4 + p5) + (p6 + p7));
            float incl = s8;
            #pragma unroll
            for (int off = 1; off < 64; off <<= 1) {
                float tv = __shfl_up(incl, off, 64);
                incl += (lane >= off) ? tv : 0.0f;
            }
            float a = carry + incl - s8;
            l[8*t+0] = a; a += p0;
            l[8*t+1] = a; a += p1;
            l[8*t+2] = a; a += p2;
            l[8*t+3] = a; a += p3;
            l[8*t+4] = a; a += p4;
            l[8*t+5] = a; a += p5;
            l[8*t+6] = a; a += p6;
            l[8*t+7] = a;
            carry += __shfl(incl, 63, 64);
        }

        if (lane == 63) qtot[q] = carry;
        __syncthreads();

        float base = c[h];
        if (q >= 1) base += qtot[0];
        if (q >= 2) base += qtot[1];
        if (q >= 3) base += qtot[2];

        uint8_t* sp = S8 + (size_t)h * D_DIM + col0;
        #pragma unroll
        for (int t = 0; t < 2; ++t) {
            unsigned qb[8];
            #pragma unroll
            for (int j = 0; j < 8; ++j)
                qb[j] = __float2uint_rn(fast_sigmoid(l[8*t+j] + base) * 255.0f);
            uint2 pk;
            pk.x = qb[0] | (qb[1] << 8) | (qb[2] << 16) | (qb[3] << 24);
            pk.y = qb[4] | (qb[5] << 8) | (qb[6] << 16) | (qb[7] << 24);
            *reinterpret_cast<uint2*>(sp + t * 512) = pk;
        }

        __syncthreads();               // all stores issued/drained
        if (tid == 0) {
            __threadfence();           // device-scope release of S row
            __hip_atomic_fetch_add(&ready[h >> 7], 1,
                                   __ATOMIC_RELEASE, __HIP_MEMORY_SCOPE_AGENT);
        }
    } else {
        // ================= VDOT (R15-exact body + spin) =================
        __shared__ uint8_t Sl[128 * 64];   // 8 KB, swizzled

        const int id  = bid - NSCAN;
        const int it  = id & 63;
        const int ht  = id >> 6;
        const int i0  = it * 64;
        const int h0  = ht * 128;
        const int wv  = tid >> 6;

        // pre-issue all 8 v row-pair loads (independent of S readiness)
        const int hl  = (lane & 31) * 4;
        const int rwb = wv * 16 + (lane >> 5);
        float4 vr[8];
        #pragma unroll
        for (int j = 0; j < 8; ++j) {
            const int row = rwb + 2 * j;
            vr[j] = *reinterpret_cast<const float4*>(
                v + (size_t)(i0 + row) * H_DIM + h0 + hl);
        }

        // wait for the 128 producer rows of this h-slab
        if (tid == 0) {
            while (__hip_atomic_load(&ready[ht], __ATOMIC_ACQUIRE,
                                     __HIP_MEMORY_SCOPE_AGENT) < 128)
                __builtin_amdgcn_s_sleep(2);
        }
        __syncthreads();

        // stage S tile: (hh, 8B-chunk c8) -> phys chunk c8 ^ ((hh>>2)&7)
        {
            const int r  = tid >> 3;
            const int c8 = tid & 7;
            #pragma unroll
            for (int p = 0; p < 4; ++p) {
                const int hh = p * 32 + r;
                uint2 d = *reinterpret_cast<const uint2*>(
                    S8 + (size_t)(h0 + hh) * D_DIM + i0 + c8 * 8);
                *reinterpret_cast<uint2*>(
                    &Sl[hh * 64 + ((c8 ^ ((hh >> 2) & 7)) << 3)]) = d;
            }
        }
        __syncthreads();

        auto sget = [&](int h_loc, int i) -> float {
            return (float)Sl[h_loc * 64
                             + ((((i) >> 3) ^ ((h_loc >> 2) & 7)) << 3) + (i & 7)];
        };

        #pragma unroll
        for (int j = 0; j < 8; ++j) {
            const int row = rwb + 2 * j;
            float acc = vr[j].x * sget(hl + 0, row)
                      + vr[j].y * sget(hl + 1, row)
                      + vr[j].z * sget(hl + 2, row)
                      + vr[j].w * sget(hl + 3, row);
            #pragma unroll
            for (int mask = 1; mask <= 16; mask <<= 1)
                acc += __shfl_xor(acc, mask, 64);
            if ((lane & 31) == 0)
                part[(size_t)ht * D_DIM + i0 + row] = acc * (1.0f / 255.0f);
        }
    }
}

// ---------------- Kernel C: out = sigmoid(b + sum_32 part) ----------------
__global__ __launch_bounds__(256, 8) void nade_out_kernel(
    const float* __restrict__ part,
    const float* __restrict__ b,
    float* __restrict__ out)
{
    const int i = blockIdx.x * 256 + threadIdx.x;
    float t = b[i];
    #pragma unroll
    for (int s = 0; s < 32; ++s)
        t += part[(size_t)s * D_DIM + i];
    out[i] = fast_sigmoid(t);
}

// ---------------- Fallback (ws too small): fused atomic (fp16 LDS) --------
__global__ __launch_bounds__(1024, 1) void nade_fused_atomic(
    const float* __restrict__ x,
    const float* __restrict__ w,
    const float* __restrict__ v,
    const float* __restrict__ c,
    float* __restrict__ logits)
{
    __shared__ __half S[16][D_DIM];   // 128 KB

    const int tid  = threadIdx.x;
    const int wv   = tid >> 6;
    const int lane = tid & 63;
    const int h0   = blockIdx.x * 16;

    const float* wrow = w + (size_t)(h0 + wv) * D_DIM + 8 * lane;
    float carry = c[h0 + wv];
    #pragma unroll
    for (int t = 0; t < 8; ++t) {
        float4 w0 = *reinterpret_cast<const float4*>(wrow + t * 512);
        float4 w1 = *reinterpret_cast<const float4*>(wrow + t * 512 + 4);
        float4 x0 = *reinterpret_cast<const float4*>(x + t * 512 + 8 * lane);
        float4 x1 = *reinterpret_cast<const float4*>(x + t * 512 + 8 * lane + 4);
        float p0 = w0.x * x0.x, p1 = w0.y * x0.y, p2 = w0.z * x0.z, p3 = w0.w * x0.w;
        float p4 = w1.x * x1.x, p5 = w1.y * x1.y, p6 = w1.z * x1.z, p7 = w1.w * x1.w;
        float s8 = ((p0 + p1) + (p2 + p3)) + ((p4 + p5) + (p6 + p7));
        float incl = s8;
        #pragma unroll
        for (int off = 1; off < 64; off <<= 1) {
            float tv = __shfl_up(incl, off, 64);
            incl += (lane >= off) ? tv : 0.0f;
        }
        float tot = __shfl(incl, 63, 64);
        float a = carry + incl - s8;
        float sg0 = fast_sigmoid(a); a += p0;
        float sg1 = fast_sigmoid(a); a += p1;
        float sg2 = fast_sigmoid(a); a += p2;
        float sg3 = fast_sigmoid(a); a += p3;
        float sg4 = fast_sigmoid(a); a += p4;
        float sg5 = fast_sigmoid(a); a += p5;
        float sg6 = fast_sigmoid(a); a += p6;
        float sg7 = fast_sigmoid(a);
        carry += tot;
        union { __half2 h2[4]; uint4 u; } P;
        P.h2[0] = __floats2half2_rn(sg0, sg1);
        P.h2[1] = __floats2half2_rn(sg2, sg3);
        P.h2[2] = __floats2half2_rn(sg4, sg5);
        P.h2[3] = __floats2half2_rn(sg6, sg7);
        *reinterpret_cast<uint4*>(&S[wv][t * 512 + 8 * lane]) = P.u;
    }
    __syncthreads();

    const int i0 = 4 * tid;
    float acc[4] = {0.f, 0.f, 0.f, 0.f};
    #pragma unroll
    for (int r = 0; r < 4; ++r) {
        const float* vp = v + (size_t)(i0 + r) * H_DIM + h0;
        float4 q0 = *reinterpret_cast<const float4*>(vp);
        float4 q1 = *reinterpret_cast<const float4*>(vp + 4);
        float4 q2 = *reinterpret_cast<const float4*>(vp + 8);
        float4 q3 = *reinterpret_cast<const float4*>(vp + 12);
        acc[r] = q0.x * __half2float(S[0][i0 + r])  + q0.y * __half2float(S[1][i0 + r])
               + q0.z * __half2float(S[2][i0 + r])  + q0.w * __half2float(S[3][i0 + r])
               + q1.x * __half2float(S[4][i0 + r])  + q1.y * __half2float(S[5][i0 + r])
               + q1.z * __half2float(S[6][i0 + r])  + q1.w * __half2float(S[7][i0 + r])
               + q2.x * __half2float(S[8][i0 + r])  + q2.y * __half2float(S[9][i0 + r])
               + q2.z * __half2float(S[10][i0 + r]) + q2.w * __half2float(S[11][i0 + r])
               + q3.x * __half2float(S[12][i0 + r]) + q3.y * __half2float(S[13][i0 + r])
               + q3.z * __half2float(S[14][i0 + r]) + q3.w * __half2float(S[15][i0 + r]);
    }
    #pragma unroll
    for (int r = 0; r < 4; ++r) atomicAdd(&logits[i0 + r], acc[r]);
}

__global__ __launch_bounds__(256, 1) void nade_final_atomic(
    const float* __restrict__ logits,
    const float* __restrict__ b,
    float* __restrict__ out)
{
    const int i = blockIdx.x * 256 + threadIdx.x;
    out[i] = fast_sigmoid(logits[i] + b[i]);
}

extern "C" void kernel_launch(void* const* d_in, const int* in_sizes, int n_in,
                              void* d_out, int out_size, void* d_ws, size_t ws_size,
                              hipStream_t stream)
{
    const float* x = (const float*)d_in[0];
    const float* w = (const float*)d_in[1];
    const float* b = (const float*)d_in[2];
    const float* v = (const float*)d_in[3];
    const float* c = (const float*)d_in[4];
    float* out = (float*)d_out;

    const size_t s_bytes    = (size_t)H_DIM * D_DIM * sizeof(uint8_t);  // 16 MB
    const size_t part_bytes = (size_t)32 * D_DIM * sizeof(float);       // 512 KB
    const size_t flag_bytes = 32 * sizeof(int);

    if (ws_size >= s_bytes + part_bytes + flag_bytes) {
        uint8_t* S8   = (uint8_t*)d_ws;
        float*   part = (float*)((char*)d_ws + s_bytes);
        int*     rdy  = (int*)((char*)d_ws + s_bytes + part_bytes);
        hipMemsetAsync(rdy, 0, flag_bytes, stream);
        nade_fused2_kernel<<<NSCAN + NVDOT, 256, 0, stream>>>(x, w, v, c, S8, part, rdy);
        nade_out_kernel<<<D_DIM / 256, 256, 0, stream>>>(part, b, out);
    } else {
        float* logits = (float*)d_ws;
        hipMemsetAsync(logits, 0, D_DIM * sizeof(float), stream);
        nade_fused_atomic<<<H_DIM / 16, 1024, 0, stream>>>(x, w, v, c, logits);
        nade_final_atomic<<<D_DIM / 256, 256, 0, stream>>>(logits, b, out);
    }
}

// Round 17
// 46.416 us; speedup vs baseline: 6.3485x; 6.3485x over previous
//
#include <hip/hip_runtime.h>
#include <hip/hip_fp16.h>
#include <stdint.h>

#define D_DIM 4096
#define H_DIM 4096

__device__ __forceinline__ float fast_sigmoid(float a) {
    return __builtin_amdgcn_rcpf(1.0f + __expf(-a));
}

// ---------------- Kernel A: quarter-split row scans -> S uint8 (R15-exact) --
__global__ __launch_bounds__(256, 8) void nade_scan_kernel(
    const float* __restrict__ x,
    const float* __restrict__ w,
    const float* __restrict__ c,
    uint8_t* __restrict__ S8)
{
    __shared__ float qtot[4];

    const int tid  = threadIdx.x;
    const int q    = tid >> 6;          // quarter 0..3
    const int lane = tid & 63;
    const int h    = blockIdx.x;
    const int col0 = q * 1024 + 8 * lane;

    const float* wp = w + (size_t)h * D_DIM + col0;
    const float* xp = x + col0;

    float4 w00 = *reinterpret_cast<const float4*>(wp);
    float4 w01 = *reinterpret_cast<const float4*>(wp + 4);
    float4 w10 = *reinterpret_cast<const float4*>(wp + 512);
    float4 w11 = *reinterpret_cast<const float4*>(wp + 512 + 4);
    float4 x00 = *reinterpret_cast<const float4*>(xp);
    float4 x01 = *reinterpret_cast<const float4*>(xp + 4);
    float4 x10 = *reinterpret_cast<const float4*>(xp + 512);
    float4 x11 = *reinterpret_cast<const float4*>(xp + 512 + 4);

    float l[16];
    float carry = 0.0f;

    #pragma unroll
    for (int t = 0; t < 2; ++t) {
        const float4 wv0 = t ? w10 : w00;
        const float4 wv1 = t ? w11 : w01;
        const float4 xv0 = t ? x10 : x00;
        const float4 xv1 = t ? x11 : x01;
        float p0 = wv0.x * xv0.x, p1 = wv0.y * xv0.y, p2 = wv0.z * xv0.z, p3 = wv0.w * xv0.w;
        float p4 = wv1.x * xv1.x, p5 = wv1.y * xv1.y, p6 = wv1.z * xv1.z, p7 = wv1.w * xv1.w;
        float s8 = ((p0 + p1) + (p2 + p3)) + ((p4 + p5) + (p6 + p7));
        float incl = s8;
        #pragma unroll
        for (int off = 1; off < 64; off <<= 1) {
            float tv = __shfl_up(incl, off, 64);
            incl += (lane >= off) ? tv : 0.0f;
        }
        float a = carry + incl - s8;     // exclusive prefix within quarter
        l[8*t+0] = a; a += p0;
        l[8*t+1] = a; a += p1;
        l[8*t+2] = a; a += p2;
        l[8*t+3] = a; a += p3;
        l[8*t+4] = a; a += p4;
        l[8*t+5] = a; a += p5;
        l[8*t+6] = a; a += p6;
        l[8*t+7] = a;
        carry += __shfl(incl, 63, 64);
    }

    if (lane == 63) qtot[q] = carry;
    __syncthreads();

    float base = c[h];
    if (q >= 1) base += qtot[0];
    if (q >= 2) base += qtot[1];
    if (q >= 3) base += qtot[2];

    uint8_t* sp = S8 + (size_t)h * D_DIM + col0;
    #pragma unroll
    for (int t = 0; t < 2; ++t) {
        unsigned qb[8];
        #pragma unroll
        for (int j = 0; j < 8; ++j)
            qb[j] = __float2uint_rn(fast_sigmoid(l[8*t+j] + base) * 255.0f);
        uint2 pk;
        pk.x = qb[0] | (qb[1] << 8) | (qb[2] << 16) | (qb[3] << 24);
        pk.y = qb[4] | (qb[5] << 8) | (qb[6] << 16) | (qb[7] << 24);
        *reinterpret_cast<uint2*>(sp + t * 512) = pk;
    }
}

// ---------------- Kernel B: vdot (R15-exact body) + direct atomic logits ----
__global__ __launch_bounds__(256, 8) void nade_vdot_kernel(
    const float* __restrict__ v,
    const uint8_t* __restrict__ S8,
    float* __restrict__ logits)
{
    __shared__ uint8_t Sl[128 * 64];   // 8 KB, swizzled

    const int tid  = threadIdx.x;
    const int it   = blockIdx.x & 63;
    const int ht   = blockIdx.x >> 6;
    const int i0   = it * 64;
    const int h0   = ht * 128;
    const int lane = tid & 63;
    const int wv   = tid >> 6;

    // stage S tile: (hh, 8B-chunk c8) -> phys chunk c8 ^ ((hh>>2)&7)
    {
        const int r  = tid >> 3;       // 32 rows per pass
        const int c8 = tid & 7;        // 8B chunk in 64B row
        #pragma unroll
        for (int p = 0; p < 4; ++p) {
            const int hh = p * 32 + r;
            uint2 d = *reinterpret_cast<const uint2*>(
                S8 + (size_t)(h0 + hh) * D_DIM + i0 + c8 * 8);
            *reinterpret_cast<uint2*>(
                &Sl[hh * 64 + ((c8 ^ ((hh >> 2) & 7)) << 3)]) = d;
        }
    }

    // pre-issue all 8 v row-pair loads (each half-wave: 512B contiguous)
    const int hl  = (lane & 31) * 4;        // lane's h-offset within tile
    const int rwb = wv * 16 + (lane >> 5);  // row base
    float4 vr[8];
    #pragma unroll
    for (int j = 0; j < 8; ++j) {
        const int row = rwb + 2 * j;
        vr[j] = *reinterpret_cast<const float4*>(
            v + (size_t)(i0 + row) * H_DIM + h0 + hl);
    }

    __syncthreads();

    auto sget = [&](int h_loc, int i) -> float {
        return (float)Sl[h_loc * 64
                         + ((((i) >> 3) ^ ((h_loc >> 2) & 7)) << 3) + (i & 7)];
    };

    #pragma unroll
    for (int j = 0; j < 8; ++j) {
        const int row = rwb + 2 * j;
        float acc = vr[j].x * sget(hl + 0, row)
                  + vr[j].y * sget(hl + 1, row)
                  + vr[j].z * sget(hl + 2, row)
                  + vr[j].w * sget(hl + 3, row);
        #pragma unroll
        for (int mask = 1; mask <= 16; mask <<= 1)
            acc += __shfl_xor(acc, mask, 64);
        if ((lane & 31) == 0)
            atomicAdd(&logits[i0 + row], acc * (1.0f / 255.0f));
    }
}

// ---------------- Kernel C: out = sigmoid(b + logits) ----------------------
__global__ __launch_bounds__(256, 8) void nade_final_kernel(
    const float* __restrict__ logits,
    const float* __restrict__ b,
    float* __restrict__ out)
{
    const int i = blockIdx.x * 256 + threadIdx.x;
    out[i] = fast_sigmoid(logits[i] + b[i]);
}

// ---------------- Fallback (ws too small): fused atomic (fp16 LDS) --------
__global__ __launch_bounds__(1024, 1) void nade_fused_atomic(
    const float* __restrict__ x,
    const float* __restrict__ w,
    const float* __restrict__ v,
    const float* __restrict__ c,
    float* __restrict__ logits)
{
    __shared__ __half S[16][D_DIM];   // 128 KB

    const int tid  = threadIdx.x;
    const int wv   = tid >> 6;
    const int lane = tid & 63;
    const int h0   = blockIdx.x * 16;

    const float* wrow = w + (size_t)(h0 + wv) * D_DIM + 8 * lane;
    float carry = c[h0 + wv];
    #pragma unroll
    for (int t = 0; t < 8; ++t) {
        float4 w0 = *reinterpret_cast<const float4*>(wrow + t * 512);
        float4 w1 = *reinterpret_cast<const float4*>(wrow + t * 512 + 4);
        float4 x0 = *reinterpret_cast<const float4*>(x + t * 512 + 8 * lane);
        float4 x1 = *reinterpret_cast<const float4*>(x + t * 512 + 8 * lane + 4);
        float p0 = w0.x * x0.x, p1 = w0.y * x0.y, p2 = w0.z * x0.z, p3 = w0.w * x0.w;
        float p4 = w1.x * x1.x, p5 = w1.y * x1.y, p6 = w1.z * x1.z, p7 = w1.w * x1.w;
        float s8 = ((p0 + p1) + (p2 + p3)) + ((p4 + p5) + (p6 + p7));
        float incl = s8;
        #pragma unroll
        for (int off = 1; off < 64; off <<= 1) {
            float tv = __shfl_up(incl, off, 64);
            incl += (lane >= off) ? tv : 0.0f;
        }
        float tot = __shfl(incl, 63, 64);
        float a = carry + incl - s8;
        float sg0 = fast_sigmoid(a); a += p0;
        float sg1 = fast_sigmoid(a); a += p1;
        float sg2 = fast_sigmoid(a); a += p2;
        float sg3 = fast_sigmoid(a); a += p3;
        float sg4 = fast_sigmoid(a); a += p4;
        float sg5 = fast_sigmoid(a); a += p5;
        float sg6 = fast_sigmoid(a); a += p6;
        float sg7 = fast_sigmoid(a);
        carry += tot;
        union { __half2 h2[4]; uint4 u; } P;
        P.h2[0] = __floats2half2_rn(sg0, sg1);
        P.h2[1] = __floats2half2_rn(sg2, sg3);
        P.h2[2] = __floats2half2_rn(sg4, sg5);
        P.h2[3] = __floats2half2_rn(sg6, sg7);
        *reinterpret_cast<uint4*>(&S[wv][t * 512 + 8 * lane]) = P.u;
    }
    __syncthreads();

    const int i0 = 4 * tid;
    float acc[4] = {0.f, 0.f, 0.f, 0.f};
    #pragma unroll
    for (int r = 0; r < 4; ++r) {
        const float* vp = v + (size_t)(i0 + r) * H_DIM + h0;
        float4 q0 = *reinterpret_cast<const float4*>(vp);
        float4 q1 = *reinterpret_cast<const float4*>(vp + 4);
        float4 q2 = *reinterpret_cast<const float4*>(vp + 8);
        float4 q3 = *reinterpret_cast<const float4*>(vp + 12);
        acc[r] = q0.x * __half2float(S[0][i0 + r])  + q0.y * __half2float(S[1][i0 + r])
               + q0.z * __half2float(S[2][i0 + r])  + q0.w * __half2float(S[3][i0 + r])
               + q1.x * __half2float(S[4][i0 + r])  + q1.y * __half2float(S[5][i0 + r])
               + q1.z * __half2float(S[6][i0 + r])  + q1.w * __half2float(S[7][i0 + r])
               + q2.x * __half2float(S[8][i0 + r])  + q2.y * __half2float(S[9][i0 + r])
               + q2.z * __half2float(S[10][i0 + r]) + q2.w * __half2float(S[11][i0 + r])
               + q3.x * __half2float(S[12][i0 + r]) + q3.y * __half2float(S[13][i0 + r])
               + q3.z * __half2float(S[14][i0 + r]) + q3.w * __half2float(S[15][i0 + r]);
    }
    #pragma unroll
    for (int r = 0; r < 4; ++r) atomicAdd(&logits[i0 + r], acc[r]);
}

extern "C" void kernel_launch(void* const* d_in, const int* in_sizes, int n_in,
                              void* d_out, int out_size, void* d_ws, size_t ws_size,
                              hipStream_t stream)
{
    const float* x = (const float*)d_in[0];
    const float* w = (const float*)d_in[1];
    const float* b = (const float*)d_in[2];
    const float* v = (const float*)d_in[3];
    const float* c = (const float*)d_in[4];
    float* out = (float*)d_out;

    const size_t s_bytes   = (size_t)H_DIM * D_DIM * sizeof(uint8_t);  // 16 MB
    const size_t lg_bytes  = (size_t)D_DIM * sizeof(float);            // 16 KB

    if (ws_size >= s_bytes + lg_bytes) {
        uint8_t* S8     = (uint8_t*)d_ws;
        float*   logits = (float*)((char*)d_ws + s_bytes);
        hipMemsetAsync(logits, 0, lg_bytes, stream);
        nade_scan_kernel<<<H_DIM, 256, 0, stream>>>(x, w, c, S8);
        nade_vdot_kernel<<<64 * 32, 256, 0, stream>>>(v, S8, logits);
        nade_final_kernel<<<D_DIM / 256, 256, 0, stream>>>(logits, b, out);
    } else {
        float* logits = (float*)d_ws;
        hipMemsetAsync(logits, 0, lg_bytes, stream);
        nade_fused_atomic<<<H_DIM / 16, 1024, 0, stream>>>(x, w, v, c, logits);
        nade_final_kernel<<<D_DIM / 256, 256, 0, stream>>>(logits, b, out);
    }
}

// Round 18
// 40.882 us; speedup vs baseline: 7.2079x; 1.1354x over previous
//
#include <hip/hip_runtime.h>
#include <hip/hip_fp16.h>
#include <stdint.h>

#define D_DIM 4096
#define H_DIM 4096

__device__ __forceinline__ float fast_sigmoid(float a) {
    return __builtin_amdgcn_rcpf(1.0f + __expf(-a));
}

// ---------------- Kernel A: quarter-split row scans -> S uint8 --------------
// grid 4096 x 256 thr (4 waves); wave q owns cols [q*1024, q*1024+1024).
// R15 structure, but the two 512-col tiles' scans are computed INDEPENDENTLY
// (pre-carry); tile0's total folds into tile1's base at sigmoid time. The two
// 6-step shuffle chains interleave -> serial latency halved.
__global__ __launch_bounds__(256, 8) void nade_scan_kernel(
    const float* __restrict__ x,
    const float* __restrict__ w,
    const float* __restrict__ c,
    uint8_t* __restrict__ S8)
{
    __shared__ float qtot[4];

    const int tid  = threadIdx.x;
    const int q    = tid >> 6;          // quarter 0..3
    const int lane = tid & 63;
    const int h    = blockIdx.x;
    const int col0 = q * 1024 + 8 * lane;

    const float* wp = w + (size_t)h * D_DIM + col0;
    const float* xp = x + col0;

    float4 w00 = *reinterpret_cast<const float4*>(wp);
    float4 w01 = *reinterpret_cast<const float4*>(wp + 4);
    float4 w10 = *reinterpret_cast<const float4*>(wp + 512);
    float4 w11 = *reinterpret_cast<const float4*>(wp + 512 + 4);
    float4 x00 = *reinterpret_cast<const float4*>(xp);
    float4 x01 = *reinterpret_cast<const float4*>(xp + 4);
    float4 x10 = *reinterpret_cast<const float4*>(xp + 512);
    float4 x11 = *reinterpret_cast<const float4*>(xp + 512 + 4);

    // tile 0 products
    float a0 = w00.x * x00.x, a1 = w00.y * x00.y, a2 = w00.z * x00.z, a3 = w00.w * x00.w;
    float a4 = w01.x * x01.x, a5 = w01.y * x01.y, a6 = w01.z * x01.z, a7 = w01.w * x01.w;
    // tile 1 products
    float b0 = w10.x * x10.x, b1 = w10.y * x10.y, b2 = w10.z * x10.z, b3 = w10.w * x10.w;
    float b4 = w11.x * x11.x, b5 = w11.y * x11.y, b6 = w11.z * x11.z, b7 = w11.w * x11.w;

    float sa = ((a0 + a1) + (a2 + a3)) + ((a4 + a5) + (a6 + a7));
    float sb = ((b0 + b1) + (b2 + b3)) + ((b4 + b5) + (b6 + b7));
    float ia = sa, ib = sb;                 // two INDEPENDENT scan chains
    #pragma unroll
    for (int off = 1; off < 64; off <<= 1) {
        float ta = __shfl_up(ia, off, 64);
        float tb = __shfl_up(ib, off, 64);
        ia += (lane >= off) ? ta : 0.0f;
        ib += (lane >= off) ? tb : 0.0f;
    }
    float tot0 = __shfl(ia, 63, 64);
    float tot1 = __shfl(ib, 63, 64);

    float l0[8], l1[8];
    {   // tile 0 local exclusive values (pre-carry)
        float a = ia - sa;
        l0[0] = a; a += a0; l0[1] = a; a += a1; l0[2] = a; a += a2; l0[3] = a; a += a3;
        l0[4] = a; a += a4; l0[5] = a; a += a5; l0[6] = a; a += a6; l0[7] = a;
    }
    {   // tile 1 local exclusive values (pre-carry, pre-tot0)
        float a = ib - sb;
        l1[0] = a; a += b0; l1[1] = a; a += b1; l1[2] = a; a += b2; l1[3] = a; a += b3;
        l1[4] = a; a += b4; l1[5] = a; a += b5; l1[6] = a; a += b6; l1[7] = a;
    }

    if (lane == 63) qtot[q] = tot0 + tot1;
    __syncthreads();

    float base0 = c[h];
    if (q >= 1) base0 += qtot[0];
    if (q >= 2) base0 += qtot[1];
    if (q >= 3) base0 += qtot[2];
    const float base1 = base0 + tot0;       // tile0 total folded here (free)

    uint8_t* sp = S8 + (size_t)h * D_DIM + col0;
    {
        unsigned qb[8];
        #pragma unroll
        for (int j = 0; j < 8; ++j)
            qb[j] = __float2uint_rn(fast_sigmoid(l0[j] + base0) * 255.0f);
        uint2 pk;
        pk.x = qb[0] | (qb[1] << 8) | (qb[2] << 16) | (qb[3] << 24);
        pk.y = qb[4] | (qb[5] << 8) | (qb[6] << 16) | (qb[7] << 24);
        *reinterpret_cast<uint2*>(sp) = pk;
    }
    {
        unsigned qb[8];
        #pragma unroll
        for (int j = 0; j < 8; ++j)
            qb[j] = __float2uint_rn(fast_sigmoid(l1[j] + base1) * 255.0f);
        uint2 pk;
        pk.x = qb[0] | (qb[1] << 8) | (qb[2] << 16) | (qb[3] << 24);
        pk.y = qb[4] | (qb[5] << 8) | (qb[6] << 16) | (qb[7] << 24);
        *reinterpret_cast<uint2*>(sp + 512) = pk;
    }
}

// ---------------- Kernel B: wave-contiguous v + swizzled uint8 LDS (R15) ----
__global__ __launch_bounds__(256, 8) void nade_vdot_kernel(
    const float* __restrict__ v,
    const uint8_t* __restrict__ S8,
    float* __restrict__ part)
{
    __shared__ uint8_t Sl[128 * 64];   // 8 KB, swizzled

    const int tid  = threadIdx.x;
    const int it   = blockIdx.x & 63;
    const int ht   = blockIdx.x >> 6;
    const int i0   = it * 64;
    const int h0   = ht * 128;
    const int lane = tid & 63;
    const int wv   = tid >> 6;

    // stage S tile: (hh, 8B-chunk c8) -> phys chunk c8 ^ ((hh>>2)&7)
    {
        const int r  = tid >> 3;       // 32 rows per pass
        const int c8 = tid & 7;        // 8B chunk in 64B row
        #pragma unroll
        for (int p = 0; p < 4; ++p) {
            const int hh = p * 32 + r;
            uint2 d = *reinterpret_cast<const uint2*>(
                S8 + (size_t)(h0 + hh) * D_DIM + i0 + c8 * 8);
            *reinterpret_cast<uint2*>(
                &Sl[hh * 64 + ((c8 ^ ((hh >> 2) & 7)) << 3)]) = d;
        }
    }

    // pre-issue all 8 v row-pair loads (each half-wave: 512B contiguous)
    const int hl  = (lane & 31) * 4;        // lane's h-offset within tile
    const int rwb = wv * 16 + (lane >> 5);  // row base
    float4 vr[8];
    #pragma unroll
    for (int j = 0; j < 8; ++j) {
        const int row = rwb + 2 * j;
        vr[j] = *reinterpret_cast<const float4*>(
            v + (size_t)(i0 + row) * H_DIM + h0 + hl);
    }

    __syncthreads();

    auto sget = [&](int h_loc, int i) -> float {
        return (float)Sl[h_loc * 64
                         + ((((i) >> 3) ^ ((h_loc >> 2) & 7)) << 3) + (i & 7)];
    };

    #pragma unroll
    for (int j = 0; j < 8; ++j) {
        const int row = rwb + 2 * j;
        float acc = vr[j].x * sget(hl + 0, row)
                  + vr[j].y * sget(hl + 1, row)
                  + vr[j].z * sget(hl + 2, row)
                  + vr[j].w * sget(hl + 3, row);
        #pragma unroll
        for (int mask = 1; mask <= 16; mask <<= 1)
            acc += __shfl_xor(acc, mask, 64);
        if ((lane & 31) == 0)
            part[(size_t)ht * D_DIM + i0 + row] = acc * (1.0f / 255.0f);
    }
}

// ---------------- Kernel C: out = sigmoid(b + sum_32 part) (R15-exact) -----
__global__ __launch_bounds__(256, 8) void nade_out_kernel(
    const float* __restrict__ part,
    const float* __restrict__ b,
    float* __restrict__ out)
{
    const int i = blockIdx.x * 256 + threadIdx.x;
    float t = b[i];
    #pragma unroll
    for (int s = 0; s < 32; ++s)
        t += part[(size_t)s * D_DIM + i];
    out[i] = fast_sigmoid(t);
}

// ---------------- Fallback (ws too small): fused atomic (fp16 LDS) --------
__global__ __launch_bounds__(1024, 1) void nade_fused_atomic(
    const float* __restrict__ x,
    const float* __restrict__ w,
    const float* __restrict__ v,
    const float* __restrict__ c,
    float* __restrict__ logits)
{
    __shared__ __half S[16][D_DIM];   // 128 KB

    const int tid  = threadIdx.x;
    const int wv   = tid >> 6;
    const int lane = tid & 63;
    const int h0   = blockIdx.x * 16;

    const float* wrow = w + (size_t)(h0 + wv) * D_DIM + 8 * lane;
    float carry = c[h0 + wv];
    #pragma unroll
    for (int t = 0; t < 8; ++t) {
        float4 w0 = *reinterpret_cast<const float4*>(wrow + t * 512);
        float4 w1 = *reinterpret_cast<const float4*>(wrow + t * 512 + 4);
        float4 x0 = *reinterpret_cast<const float4*>(x + t * 512 + 8 * lane);
        float4 x1 = *reinterpret_cast<const float4*>(x + t * 512 + 8 * lane + 4);
        float p0 = w0.x * x0.x, p1 = w0.y * x0.y, p2 = w0.z * x0.z, p3 = w0.w * x0.w;
        float p4 = w1.x * x1.x, p5 = w1.y * x1.y, p6 = w1.z * x1.z, p7 = w1.w * x1.w;
        float s8 = ((p0 + p1) + (p2 + p3)) + ((p4 + p5) + (p6 + p7));
        float incl = s8;
        #pragma unroll
        for (int off = 1; off < 64; off <<= 1) {
            float tv = __shfl_up(incl, off, 64);
            incl += (lane >= off) ? tv : 0.0f;
        }
        float tot = __shfl(incl, 63, 64);
        float a = carry + incl - s8;
        float sg0 = fast_sigmoid(a); a += p0;
        float sg1 = fast_sigmoid(a); a += p1;
        float sg2 = fast_sigmoid(a); a += p2;
        float sg3 = fast_sigmoid(a); a += p3;
        float sg4 = fast_sigmoid(a); a += p4;
        float sg5 = fast_sigmoid(a); a += p5;
        float sg6 = fast_sigmoid(a); a += p6;
        float sg7 = fast_sigmoid(a);
        carry += tot;
        union { __half2 h2[4]; uint4 u; } P;
        P.h2[0] = __floats2half2_rn(sg0, sg1);
        P.h2[1] = __floats2half2_rn(sg2, sg3);
        P.h2[2] = __floats2half2_rn(sg4, sg5);
        P.h2[3] = __floats2half2_rn(sg6, sg7);
        *reinterpret_cast<uint4*>(&S[wv][t * 512 + 8 * lane]) = P.u;
    }
    __syncthreads();

    const int i0 = 4 * tid;
    float acc[4] = {0.f, 0.f, 0.f, 0.f};
    #pragma unroll
    for (int r = 0; r < 4; ++r) {
        const float* vp = v + (size_t)(i0 + r) * H_DIM + h0;
        float4 q0 = *reinterpret_cast<const float4*>(vp);
        float4 q1 = *reinterpret_cast<const float4*>(vp + 4);
        float4 q2 = *reinterpret_cast<const float4*>(vp + 8);
        float4 q3 = *reinterpret_cast<const float4*>(vp + 12);
        acc[r] = q0.x * __half2float(S[0][i0 + r])  + q0.y * __half2float(S[1][i0 + r])
               + q0.z * __half2float(S[2][i0 + r])  + q0.w * __half2float(S[3][i0 + r])
               + q1.x * __half2float(S[4][i0 + r])  + q1.y * __half2float(S[5][i0 + r])
               + q1.z * __half2float(S[6][i0 + r])  + q1.w * __half2float(S[7][i0 + r])
               + q2.x * __half2float(S[8][i0 + r])  + q2.y * __half2float(S[9][i0 + r])
               + q2.z * __half2float(S[10][i0 + r]) + q2.w * __half2float(S[11][i0 + r])
               + q3.x * __half2float(S[12][i0 + r]) + q3.y * __half2float(S[13][i0 + r])
               + q3.z * __half2float(S[14][i0 + r]) + q3.w * __half2float(S[15][i0 + r]);
    }
    #pragma unroll
    for (int r = 0; r < 4; ++r) atomicAdd(&logits[i0 + r], acc[r]);
}

__global__ __launch_bounds__(256, 1) void nade_final_atomic(
    const float* __restrict__ logits,
    const float* __restrict__ b,
    float* __restrict__ out)
{
    const int i = blockIdx.x * 256 + threadIdx.x;
    out[i] = fast_sigmoid(logits[i] + b[i]);
}

extern "C" void kernel_launch(void* const* d_in, const int* in_sizes, int n_in,
                              void* d_out, int out_size, void* d_ws, size_t ws_size,
                              hipStream_t stream)
{
    const float* x = (const float*)d_in[0];
    const float* w = (const float*)d_in[1];
    const float* b = (const float*)d_in[2];
    const float* v = (const float*)d_in[3];
    const float* c = (const float*)d_in[4];
    float* out = (float*)d_out;

    const size_t s_bytes    = (size_t)H_DIM * D_DIM * sizeof(uint8_t);  // 16 MB
    const size_t part_bytes = (size_t)32 * D_DIM * sizeof(float);       // 512 KB

    if (ws_size >= s_bytes + part_bytes) {
        uint8_t* S8   = (uint8_t*)d_ws;
        float*   part = (float*)((char*)d_ws + s_bytes);
        nade_scan_kernel<<<H_DIM, 256, 0, stream>>>(x, w, c, S8);
        nade_vdot_kernel<<<64 * 32, 256, 0, stream>>>(v, S8, part);
        nade_out_kernel<<<D_DIM / 256, 256, 0, stream>>>(part, b, out);
    } else {
        float* logits = (float*)d_ws;
        hipMemsetAsync(logits, 0, D_DIM * sizeof(float), stream);
        nade_fused_atomic<<<H_DIM / 16, 1024, 0, stream>>>(x, w, v, c, logits);
        nade_final_atomic<<<D_DIM / 256, 256, 0, stream>>>(logits, b, out);
    }
}